// Round 1
// baseline (32.024 us; speedup 1.0000x reference)
//
#include <hip/hip_runtime.h>
#include <hip/hip_bf16.h>

// HungarianMatcher cost matrix:
//   C[i, j] = REG_W * (4/2) * L1(pred_pts[i], gt_pts[j])
//           + CLS_W * (pos_cost - neg_cost)(sigmoid(pred_class[i, tid_j]))
// with i in [0, bs*Q), j in [0, bs*T), num_classes = 2.
//
// Memory-bound on the 134 MB fp32 output. Each block owns RPB=4 rows and
// streams all columns; target data is read once per column chunk and reused
// across the 4 rows from registers. All stores are float4-coalesced.

#define ALPHA     0.25f
#define GAMMA_2   /* gamma==2 -> squares */ 1
#define EPS_F     1e-8f
#define CLS_W     2.0f
#define REG_W     5.0f

__device__ __forceinline__ float focal_cc(float x) {
    // p = sigmoid(x); returns CLS_W * (pos_cost - neg_cost)
    float p  = 1.0f / (1.0f + expf(-x));
    float om = 1.0f - p;
    float pos = ALPHA        * om * om * (-logf(p  + EPS_F));
    float neg = (1.0f-ALPHA) * p  * p  * (-logf(om + EPS_F));
    return CLS_W * (pos - neg);
}

template <int RPB>
__global__ __launch_bounds__(256)
void hm_cost_kernel(const float2* __restrict__ pred_class,   // [rows] as float2 (2 classes)
                    const float2* __restrict__ pred_pts,     // [rows] as float2
                    const int*    __restrict__ tgt_ids,      // [cols]
                    const float2* __restrict__ tgt_pts,      // [cols] as float2
                    float*        __restrict__ out,          // [rows, cols]
                    int cols) {
    const int row0 = blockIdx.x * RPB;

    float px[RPB], py[RPB], cc0[RPB], cc1[RPB];
#pragma unroll
    for (int r = 0; r < RPB; ++r) {
        const int i   = row0 + r;
        const float2 x  = pred_class[i];
        const float2 pt = pred_pts[i];
        px[r]  = pt.x;
        py[r]  = pt.y;
        cc0[r] = focal_cc(x.x);
        cc1[r] = focal_cc(x.y);
    }

    const int cols4 = cols >> 2;                 // float4 granularity
    const float4* tp4 = reinterpret_cast<const float4*>(tgt_pts);
    const int4*   id4 = reinterpret_cast<const int4*>(tgt_ids);
    float4* out4 = reinterpret_cast<float4*>(out);

    for (int j4 = threadIdx.x; j4 < cols4; j4 += blockDim.x) {
        const float4 tpA = tp4[j4 * 2 + 0];      // tx0, ty0, tx1, ty1
        const float4 tpB = tp4[j4 * 2 + 1];      // tx2, ty2, tx3, ty3
        const int4   id  = id4[j4];

#pragma unroll
        for (int r = 0; r < RPB; ++r) {
            const float qx = px[r], qy = py[r];
            const float c0 = cc0[r], c1 = cc1[r];
            float4 o;
            // REG_W * (4/2) * L1 = 10 * L1
            o.x = 10.0f * (fabsf(qx - tpA.x) + fabsf(qy - tpA.y)) + (id.x ? c1 : c0);
            o.y = 10.0f * (fabsf(qx - tpA.z) + fabsf(qy - tpA.w)) + (id.y ? c1 : c0);
            o.z = 10.0f * (fabsf(qx - tpB.x) + fabsf(qy - tpB.y)) + (id.z ? c1 : c0);
            o.w = 10.0f * (fabsf(qx - tpB.z) + fabsf(qy - tpB.w)) + (id.w ? c1 : c0);
            out4[(size_t)(row0 + r) * cols4 + j4] = o;
        }
    }
}

extern "C" void kernel_launch(void* const* d_in, const int* in_sizes, int n_in,
                              void* d_out, int out_size, void* d_ws, size_t ws_size,
                              hipStream_t stream) {
    // inputs (setup_inputs order): pred_class [bs,Q,2] f32, pred_points [bs,Q,2] f32,
    //                              gt_class [bs,T] int, gt_points [bs,T,2] f32
    const float2* pred_class = reinterpret_cast<const float2*>(d_in[0]);
    const float2* pred_pts   = reinterpret_cast<const float2*>(d_in[1]);
    const int*    tgt_ids    = reinterpret_cast<const int*>(d_in[2]);
    const float2* tgt_pts    = reinterpret_cast<const float2*>(d_in[3]);
    float*        out        = reinterpret_cast<float*>(d_out);

    const int rows = in_sizes[1] / 2;   // bs*Q   (pred_points has 2 coords)
    const int cols = in_sizes[2];       // bs*T

    constexpr int RPB = 4;
    const int grid = rows / RPB;        // 8192/4 = 2048 blocks
    hm_cost_kernel<RPB><<<grid, 256, 0, stream>>>(
        pred_class, pred_pts, tgt_ids, tgt_pts, out, cols);
}

// Round 3
// 28.072 us; speedup vs baseline: 1.1408x; 1.1408x over previous
//
#include <hip/hip_runtime.h>
#include <hip/hip_bf16.h>

// HungarianMatcher cost matrix:
//   C[i, j] = 10 * L1(pred_pts[i], gt_pts[j])
//           + 2 * (pos_cost - neg_cost)(sigmoid(pred_class[i, tid_j]))
// i in [0, bs*Q=8192), j in [0, bs*T=4096), num_classes = 2.
//
// Pure HBM-write-bound (134 MB out, ~150 KB in). This round:
//  - nontemporal float4 stores via native ext_vector_type (HIP float4 is a
//    class type that __builtin_nontemporal_store rejects)
//  - per-row focal scalars computed ONCE per block (4 lanes), shared via LDS.

#define ALPHA  0.25f
#define EPS_F  1e-8f
#define CLS_W  2.0f

typedef float f32x4 __attribute__((ext_vector_type(4)));

__device__ __forceinline__ float focal_cc(float x) {
    // p = sigmoid(x); returns CLS_W * (pos_cost - neg_cost), gamma = 2
    float p  = 1.0f / (1.0f + expf(-x));
    float om = 1.0f - p;
    float pos = ALPHA          * om * om * (-logf(p  + EPS_F));
    float neg = (1.0f - ALPHA) * p  * p  * (-logf(om + EPS_F));
    return CLS_W * (pos - neg);
}

template <int RPB>
__global__ __launch_bounds__(256)
void hm_cost_kernel(const float2* __restrict__ pred_class,   // [rows] (2 classes)
                    const float2* __restrict__ pred_pts,     // [rows]
                    const int*    __restrict__ tgt_ids,      // [cols]
                    const float2* __restrict__ tgt_pts,      // [cols]
                    float*        __restrict__ out,          // [rows, cols]
                    int cols) {
    const int row0 = blockIdx.x * RPB;

    // One lane per row computes the 4 per-row scalars; everyone reads from LDS.
    __shared__ float s_px[RPB], s_py[RPB], s_cc0[RPB], s_cc1[RPB];
    if (threadIdx.x < RPB) {
        const int r = threadIdx.x;
        const float2 x  = pred_class[row0 + r];
        const float2 pt = pred_pts[row0 + r];
        s_px[r]  = pt.x;
        s_py[r]  = pt.y;
        s_cc0[r] = focal_cc(x.x);
        s_cc1[r] = focal_cc(x.y);
    }
    __syncthreads();

    float px[RPB], py[RPB], cc0[RPB], cc1[RPB];
#pragma unroll
    for (int r = 0; r < RPB; ++r) {
        px[r] = s_px[r];  py[r] = s_py[r];
        cc0[r] = s_cc0[r]; cc1[r] = s_cc1[r];
    }

    const int cols4 = cols >> 2;                 // float4 granularity
    const float4* tp4 = reinterpret_cast<const float4*>(tgt_pts);
    const int4*   id4 = reinterpret_cast<const int4*>(tgt_ids);
    f32x4* out4 = reinterpret_cast<f32x4*>(out);

    for (int j4 = threadIdx.x; j4 < cols4; j4 += blockDim.x) {
        const float4 tpA = tp4[j4 * 2 + 0];      // tx0, ty0, tx1, ty1
        const float4 tpB = tp4[j4 * 2 + 1];      // tx2, ty2, tx3, ty3
        const int4   id  = id4[j4];

#pragma unroll
        for (int r = 0; r < RPB; ++r) {
            const float qx = px[r], qy = py[r];
            const float c0 = cc0[r], c1 = cc1[r];
            f32x4 o;
            o.x = 10.0f * (fabsf(qx - tpA.x) + fabsf(qy - tpA.y)) + (id.x ? c1 : c0);
            o.y = 10.0f * (fabsf(qx - tpA.z) + fabsf(qy - tpA.w)) + (id.y ? c1 : c0);
            o.z = 10.0f * (fabsf(qx - tpB.x) + fabsf(qy - tpB.y)) + (id.z ? c1 : c0);
            o.w = 10.0f * (fabsf(qx - tpB.z) + fabsf(qy - tpB.w)) + (id.w ? c1 : c0);
            __builtin_nontemporal_store(o, &out4[(size_t)(row0 + r) * cols4 + j4]);
        }
    }
}

extern "C" void kernel_launch(void* const* d_in, const int* in_sizes, int n_in,
                              void* d_out, int out_size, void* d_ws, size_t ws_size,
                              hipStream_t stream) {
    // inputs: pred_class [bs,Q,2] f32, pred_points [bs,Q,2] f32,
    //         gt_class [bs,T] int32, gt_points [bs,T,2] f32
    const float2* pred_class = reinterpret_cast<const float2*>(d_in[0]);
    const float2* pred_pts   = reinterpret_cast<const float2*>(d_in[1]);
    const int*    tgt_ids    = reinterpret_cast<const int*>(d_in[2]);
    const float2* tgt_pts    = reinterpret_cast<const float2*>(d_in[3]);
    float*        out        = reinterpret_cast<float*>(d_out);

    const int rows = in_sizes[1] / 2;   // bs*Q
    const int cols = in_sizes[2];       // bs*T

    constexpr int RPB = 4;
    const int grid = rows / RPB;        // 2048 blocks
    hm_cost_kernel<RPB><<<grid, 256, 0, stream>>>(
        pred_class, pred_pts, tgt_ids, tgt_pts, out, cols);
}